// Round 7
// baseline (214.149 us; speedup 1.0000x reference)
//
#include <hip/hip_runtime.h>

// contract(off): numpy-emulating fp32 ops (esq, rescue zsq/dist) must round mul
// and add separately. Explicit fmaf/fma and MFMA are unaffected.
#pragma clang fp contract(off)

#define K_CODES 512
#define D_DIM 256
#define NPIX 65536
#define TAU 3e-4f
#define STRA 264   // A LDS row stride in shorts: 528 B, 16B-aligned
#define CMAX 16    // max stored rescue candidates per pixel (overflow -> full scan)
#define PPB  32    // pixels per block (r6: was 64; halves VGPR+LDS -> 3 blocks/CU)
// z layout [B=64, D=256, H*W=1024]; pixel n = b*1024 + hw.

typedef __attribute__((ext_vector_type(8))) short bf16x8;
typedef __attribute__((ext_vector_type(4))) float f32x4;

// B fragments pre-packed in wave-lane order (validated r8): index
// ((kc*32 + nb)*64 + lane)*8 holds B[n = nb*16 + (lane&15)][k = kc*32 + (lane>>4)*8 + j].
__device__ unsigned short g_bph[8 * 32 * 64 * 8];  // hi
__device__ unsigned short g_bpl[8 * 32 * 64 * 8];  // lo
__device__ float4 g_cbF4[(D_DIM / 4) * K_CODES];   // fp32 cb for rescue (exact)
__device__ float  g_esq[K_CODES];                  // numpy-pairwise fp32 ||e_k||^2
__device__ int    g_list[NPIX];                    // n | (ncand<<16) | overflow<<31
__device__ int    g_cand[NPIX * CMAX];             // candidate code ids per flagged pixel
__device__ int    g_count;

// SESSION LEDGER (do not re-try):
//  r0: acc[4][2] two-half split + launch_bounds(512,4) -> spills (90 MB scratch), 112 us. REVERTED.
//  r1: x2-unrolled K-loop, 2 named B bufs, setprio -> VGPR 76+64 > 128 budget -> 1 block/CU,
//      140 us. Per-occupancy efficiency IDENTICAL (0.65) -> occupancy is the only pass1 lever.
//  r3: candidate-set rescue (scan ~3 codes instead of 512). PASSED, 179.0 -> validated.
//  r4: rescue fused INTO pass1 -> nondeterministic post-timing divergence (absmax 512,
//      poison-retained output). Root cause never identified. DO NOT re-attempt in-kernel
//      rescue without a causal theory + race screen.
//  r5: byte-identical revert to r3. PASSED, 177.0 us. pass1 84.9, VGPR 56, occ 38.5%.
//  r6 (THIS): 32-px blocks -> acc[2][4]=32 AGPR, LDS 38 KB, target <=85 VGPR -> 24 waves/CU.
//      Per-element MFMA chain bit-identical to golden (same K-order, same fragments).

static __device__ __forceinline__ unsigned short f2bf(float x) {
    unsigned u = __float_as_uint(x);
    return (unsigned short)((u + 0x7FFFu + ((u >> 16) & 1u)) >> 16);   // RNE
}
static __device__ __forceinline__ float bf2f(unsigned short h) {
    return __uint_as_float((unsigned)h << 16);
}

// 64 blocks x 256: thread = (k, kc, quad). Numerics byte-identical to the
// validated 16-block version (same f2bf, same esq pairwise order, same cbF4).
__global__ __launch_bounds__(256) void prep_cb(const float* __restrict__ cb) {
    if (blockIdx.x == 0 && threadIdx.x == 0) g_count = 0;
    const int gt   = blockIdx.x * 256 + threadIdx.x;   // 0..16383
    const int k    = gt >> 5;                          // 0..511
    const int sub  = gt & 31;
    const int kc   = sub >> 2;                         // 0..7
    const int quad = sub & 3;                          // 0..3
    const float* row = cb + k * D_DIM;
    const int nb = k >> 4, nl = k & 15;
    const int lane = quad * 16 + nl;

    unsigned short h8[8], l8[8];
    #pragma unroll
    for (int j = 0; j < 8; ++j) {
        float x = row[kc * 32 + quad * 8 + j];
        h8[j] = f2bf(x);
        l8[j] = f2bf(x - bf2f(h8[j]));   // x-hi exact (Sterbenz)
    }
    const int dst = ((kc * 32 + nb) * 64 + lane) * 8;
    *(uint4*)&g_bph[dst] = *(uint4*)&h8[0];
    *(uint4*)&g_bpl[dst] = *(uint4*)&l8[0];

    // cbF4 scatter distributed: each (k,sub) covers dq = 2*sub, 2*sub+1.
    #pragma unroll
    for (int u = 0; u < 2; ++u) {
        const int dq = sub * 2 + u;
        g_cbF4[dq * K_CODES + k] = make_float4(row[4*dq], row[4*dq+1], row[4*dq+2], row[4*dq+3]);
    }

    if (sub == 0) {
        // e_sq = np.sum(row*row): pairwise n=256 -> p(0:128)+p(128:256); 8 accums each.
        float s[2];
        for (int blk = 0; blk < 2; ++blk) {
            const float* a = row + blk * 128;
            float r[8];
            #pragma unroll
            for (int j = 0; j < 8; ++j) { float x = a[j]; r[j] = x * x; }
            for (int i = 8; i < 128; i += 8)
                #pragma unroll
                for (int j = 0; j < 8; ++j) { float x = a[i + j]; r[j] += x * x; }
            s[blk] = ((r[0] + r[1]) + (r[2] + r[3])) + ((r[4] + r[5]) + (r[6] + r[7]));
        }
        g_esq[k] = s[0] + s[1];
    }
}

// pass1 r6: golden K-loop chain at 32 pixels/block. Wave w still owns codes
// [w*64,(w+1)*64); ti now 0..1 (32 px). Per output element the MFMA
// accumulation sees identical fragments in identical order -> dists
// bit-identical to the validated golden kernel. Target: VGPR <= 85
// (32 acc + ~50 arch) and LDS 38 KB -> 3 blocks/CU = 24 waves (16 before).
// NO launch_bounds min-wave arg (r0: forced caps spill catastrophically).
__global__ __launch_bounds__(512) void pass1_fused(const float* __restrict__ z,
                                                   int* __restrict__ out) {
    __shared__ unsigned short Az[2][PPB * STRA];  // [0]=hi, [1]=lo ; [px][d]
    __shared__ float s_mn[8][PPB];
    __shared__ int   s_ixl[8][PPB];
    __shared__ float s_gm[PPB];
    __shared__ int   s_gi[PPB];
    __shared__ int   s_ccn[PPB];
    __shared__ int   s_cand[PPB][CMAX];

    const int lane = threadIdx.x & 63;
    const int w    = __builtin_amdgcn_readfirstlane((int)(threadIdx.x >> 6));
    const int l16  = lane & 15, quad = lane >> 4;
    const int n0   = (int)blockIdx.x * PPB;       // 32 | 1024 -> same b

    // ---- Prologue: stage A. Wave w covers d-chunk [w*32,(w+1)*32) for all
    // 32 px: px = lane&31, dh = lane>>5 picks 16-d half; two 8-d sub-chunks
    // keep the register high-water low (x[8] not x[16]). Element-wise f2bf
    // identical to golden; every (px,d) written exactly once.
    {
        const float* zb0 = z + ((size_t)(n0 >> 10) << 18) + (n0 & 1023);
        const int px = lane & 31, dh = lane >> 5;
        #pragma unroll
        for (int hh = 0; hh < 2; ++hh) {
            const int d0 = w * 32 + dh * 16 + hh * 8;
            float x[8];
            #pragma unroll
            for (int j = 0; j < 8; ++j)
                x[j] = zb0[(size_t)(d0 + j) * 1024 + px];   // 128B contiguous per 32 lanes
            unsigned short h[8], l[8];
            #pragma unroll
            for (int j = 0; j < 8; ++j) {
                h[j] = f2bf(x[j]);
                l[j] = f2bf(x[j] - bf2f(h[j]));
            }
            const int o = px * STRA + d0;
            *(uint4*)&Az[0][o] = *(uint4*)&h[0];
            *(uint4*)&Az[1][o] = *(uint4*)&l[0];
        }
    }
    __syncthreads();

    f32x4 acc[2][4];
    #pragma unroll
    for (int i = 0; i < 2; ++i)
        #pragma unroll
        for (int j = 0; j < 4; ++j)
            acc[i][j] = (f32x4){0.f, 0.f, 0.f, 0.f};

    // ---- K-loop: 24 steps, no barriers. seg0: zh*ch, seg1: zh*cl, seg2: zl*ch
    // (chain identical to golden). B prefetched one step ahead, same as golden.
    bf16x8 bcur[4];
    #pragma unroll
    for (int tj = 0; tj < 4; ++tj)
        bcur[tj] = *(const bf16x8*)&g_bph[((size_t)(0 * 32 + w * 4 + tj) * 64 + lane) * 8];

    for (int st = 0; st < 24; ++st) {
        const int seg = st >> 3;
        const int kc  = st & 7;
        const unsigned short* As = Az[(seg == 2) ? 1 : 0];

        bf16x8 bnxt[4];
        if (st < 23) {
            const int sp = st + 1;
            const unsigned short* bp = ((sp >> 3) == 1) ? g_bpl : g_bph;
            const int kcn = sp & 7;
            #pragma unroll
            for (int tj = 0; tj < 4; ++tj)   // 1 KB coalesced per wave, L2-hot
                bnxt[tj] = *(const bf16x8*)&bp[((size_t)(kcn * 32 + w * 4 + tj) * 64 + lane) * 8];
        }

        bf16x8 af[2];
        #pragma unroll
        for (int ti = 0; ti < 2; ++ti)
            af[ti] = *(const bf16x8*)&As[(ti * 16 + l16) * STRA + kc * 32 + quad * 8];

        #pragma unroll
        for (int ti = 0; ti < 2; ++ti)
            #pragma unroll
            for (int tj = 0; tj < 4; ++tj)
                acc[ti][tj] = __builtin_amdgcn_mfma_f32_16x16x32_bf16(
                    af[ti], bcur[tj], acc[ti][tj], 0, 0, 0);

        if (st < 23) {
            #pragma unroll
            for (int tj = 0; tj < 4; ++tj) bcur[tj] = bnxt[tj];
        }
    }

    // ---- Epilogue (golden, ranges re-derived for 32 px). C/D: col=lane&15 -> n,
    // row=quad*4+r -> m; m = ti*16 + quad*4 + r in [0,32).
    float esqv[4];
    #pragma unroll
    for (int tj = 0; tj < 4; ++tj) esqv[tj] = g_esq[w * 64 + tj * 16 + l16];
    #pragma unroll
    for (int ti = 0; ti < 2; ++ti)
        #pragma unroll
        for (int tj = 0; tj < 4; ++tj)
            #pragma unroll
            for (int r = 0; r < 4; ++r)
                acc[ti][tj][r] = fmaf(-2.0f, acc[ti][tj][r], esqv[tj]);

    #pragma unroll
    for (int ti = 0; ti < 2; ++ti) {
        #pragma unroll
        for (int r = 0; r < 4; ++r) {
            float bv = __builtin_inff(); int bn = 0x7FFFFFFF;
            #pragma unroll
            for (int tj = 0; tj < 4; ++tj) {
                float s = acc[ti][tj][r];
                int nn = w * 64 + tj * 16 + l16;
                if (s < bv || (s == bv && nn < bn)) { bv = s; bn = nn; }
            }
            #pragma unroll
            for (int off = 1; off <= 8; off <<= 1) {
                float ov = __shfl_xor(bv, off); int on = __shfl_xor(bn, off);
                if (ov < bv || (ov == bv && on < bn)) { bv = ov; bn = on; }
            }
            if (l16 == 0) {
                int m = ti * 16 + quad * 4 + r;
                s_mn[w][m] = bv; s_ixl[w][m] = bn;
            }
        }
    }
    __syncthreads();

    if (threadIdx.x < PPB) {
        int m = threadIdx.x;
        float gm = s_mn[0][m]; int gi = s_ixl[0][m];
        #pragma unroll
        for (int q = 1; q < 8; ++q) {
            float v = s_mn[q][m]; int ii = s_ixl[q][m];
            if (v < gm || (v == gm && ii < gi)) { gm = v; gi = ii; }
        }
        s_gm[m] = gm; s_gi[m] = gi; s_ccn[m] = 0;
    }
    __syncthreads();

    // Candidate-append pass (validated r3): records {codes with dist < gm+TAU}.
    // List order is atomic-nondeterministic; rescue's lexicographic argmin is
    // order-independent.
    #pragma unroll
    for (int ti = 0; ti < 2; ++ti) {
        #pragma unroll
        for (int r = 0; r < 4; ++r) {
            const int m = ti * 16 + quad * 4 + r;
            const float thr = s_gm[m] + TAU;
            #pragma unroll
            for (int tj = 0; tj < 4; ++tj) {
                if (acc[ti][tj][r] < thr) {
                    int slot = atomicAdd(&s_ccn[m], 1);
                    if (slot < CMAX) s_cand[m][slot] = w * 64 + tj * 16 + l16;
                }
            }
        }
    }
    __syncthreads();

    if (threadIdx.x < PPB) {
        int m = threadIdx.x;
        out[n0 + m] = s_gi[m];
        int cnt = s_ccn[m];
        if (cnt >= 2) {
            int pos = atomicAdd(&g_count, 1);
            int ncS = cnt > CMAX ? CMAX : cnt;
            g_list[pos] = (n0 + m) | (ncS << 16) | (cnt > CMAX ? (int)0x80000000 : 0);
            for (int i = 0; i < ncS; ++i) g_cand[pos * CMAX + i] = s_cand[m][i];
        }
    }
}

// Rescue: numpy-bit-exact (validated r3/r5). One wave per flagged pixel.
// Only the recorded candidate codes are recomputed (lane i -> cand[i]);
// per-code math is VERBATIM the validated full-scan body, so each
// candidate's dist is bit-identical to what the full scan would produce.
// The TAU guarantee puts every possible numpy argmin in the candidate set.
// Overflow (>CMAX) pixels take the original full-512 path.
__global__ __launch_bounds__(256) void rescue_kernel(const float* __restrict__ z,
                                                     int* __restrict__ out) {
    const int lane = threadIdx.x & 63;
    const int wg   = (int)blockIdx.x * 4 + (int)(threadIdx.x >> 6);
    const int nw   = (int)gridDim.x * 4;
    const int count = g_count;

    for (int it = wg; it < count; it += nw) {
        const int entry = g_list[it];
        const int n  = entry & 0xFFFF;
        const int nc = (entry >> 16) & 0x1F;
        const bool full = entry < 0;               // overflow -> full scan
        const float* zp = z + ((size_t)(n >> 10) << 18) + (n & 1023);

        float zf[4], xsq[4];
        #pragma unroll
        for (int q = 0; q < 4; ++q) zf[q] = zp[(size_t)((q << 6) + lane) << 10];
        #pragma unroll
        for (int q = 0; q < 4; ++q) xsq[q] = zf[q] * zf[q];

        // numpy pairwise zsq via shuffles (bit-exact, validated r5)
        const int j = lane & 7;
        float r0 = __shfl(xsq[0], j);
        #pragma unroll
        for (int t = 1; t < 8; ++t) r0 += __shfl(xsq[0], 8 * t + j);
        #pragma unroll
        for (int t = 0; t < 8; ++t) r0 += __shfl(xsq[1], 8 * t + j);
        float r1 = __shfl(xsq[2], j);
        #pragma unroll
        for (int t = 1; t < 8; ++t) r1 += __shfl(xsq[2], 8 * t + j);
        #pragma unroll
        for (int t = 0; t < 8; ++t) r1 += __shfl(xsq[3], 8 * t + j);
        r0 = r0 + __shfl_xor(r0, 1); r0 = r0 + __shfl_xor(r0, 2); r0 = r0 + __shfl_xor(r0, 4);
        r1 = r1 + __shfl_xor(r1, 1); r1 = r1 + __shfl_xor(r1, 2); r1 = r1 + __shfl_xor(r1, 4);
        const float zsq = r0 + r1;

        float best = __builtin_inff(); int bi = 0x7FFFFFFF;

        if (!full) {
            // Candidate path: lane i handles candidate i (lanes >= nc duplicate
            // candidate 0 -- idempotent under (dist, idx) min-reduce).
            const int kk = g_cand[it * CMAX + (lane < nc ? lane : 0)];
            double a8a = 0.0, a8b = 0.0;
            for (int dq = 0; dq < D_DIM / 4; ++dq) {
                const int d0 = dq * 4;
                double zd0 = (double)__shfl(zf[(d0    ) >> 6], (d0    ) & 63);
                double zd1 = (double)__shfl(zf[(d0 + 1) >> 6], (d0 + 1) & 63);
                double zd2 = (double)__shfl(zf[(d0 + 2) >> 6], (d0 + 2) & 63);
                double zd3 = (double)__shfl(zf[(d0 + 3) >> 6], (d0 + 3) & 63);
                float4 c4 = g_cbF4[dq * K_CODES + kk];
                a8a = fma((double)c4.x, zd0, a8a);
                a8a = fma((double)c4.y, zd1, a8a);
                a8b = fma((double)c4.z, zd2, a8b);
                a8b = fma((double)c4.w, zd3, a8b);
            }
            float c32 = (float)(a8a + a8b);
            float t = zsq - 2.0f * c32;
            best = t + g_esq[kk];
            bi = kk;
        } else {
            // Original full-512 path, verbatim (overflow fallback).
            double a8a[8], a8b[8];
            #pragma unroll
            for (int jj = 0; jj < 8; ++jj) { a8a[jj] = 0.0; a8b[jj] = 0.0; }
            for (int dq = 0; dq < D_DIM / 4; ++dq) {
                const int d0 = dq * 4;
                double zd0 = (double)__shfl(zf[(d0    ) >> 6], (d0    ) & 63);
                double zd1 = (double)__shfl(zf[(d0 + 1) >> 6], (d0 + 1) & 63);
                double zd2 = (double)__shfl(zf[(d0 + 2) >> 6], (d0 + 2) & 63);
                double zd3 = (double)__shfl(zf[(d0 + 3) >> 6], (d0 + 3) & 63);
                #pragma unroll
                for (int jj = 0; jj < 8; ++jj) {
                    float4 c4 = g_cbF4[dq * K_CODES + lane + (jj << 6)];
                    a8a[jj] = fma((double)c4.x, zd0, a8a[jj]);
                    a8a[jj] = fma((double)c4.y, zd1, a8a[jj]);
                    a8b[jj] = fma((double)c4.z, zd2, a8b[jj]);
                    a8b[jj] = fma((double)c4.w, zd3, a8b[jj]);
                }
            }
            #pragma unroll
            for (int jj = 0; jj < 8; ++jj) {
                int kk = lane + (jj << 6);
                float c32 = (float)(a8a[jj] + a8b[jj]);
                float t = zsq - 2.0f * c32;
                float dist = t + g_esq[kk];
                if (dist < best || (dist == best && kk < bi)) { best = dist; bi = kk; }
            }
        }

        #pragma unroll
        for (int off = 32; off; off >>= 1) {
            float ob = __shfl_xor(best, off);
            int   oi = __shfl_xor(bi, off);
            if (ob < best || (ob == best && oi < bi)) { best = ob; bi = oi; }
        }
        if (lane == 0) out[n] = bi;
    }
}

extern "C" void kernel_launch(void* const* d_in, const int* in_sizes, int n_in,
                              void* d_out, int out_size, void* d_ws, size_t ws_size,
                              hipStream_t stream) {
    const float* z_e_x    = (const float*)d_in[0];   // [64, 256, 32, 32] fp32
    const float* codebook = (const float*)d_in[1];   // [512, 256] fp32
    int* out = (int*)d_out;                          // [65536] int32

    prep_cb<<<dim3(64), dim3(256), 0, stream>>>(codebook);
    pass1_fused<<<dim3(NPIX / PPB), dim3(512), 0, stream>>>(z_e_x, out);
    rescue_kernel<<<dim3(512), dim3(256), 0, stream>>>(z_e_x, out);
}

// Round 8
// 175.919 us; speedup vs baseline: 1.2173x; 1.2173x over previous
//
#include <hip/hip_runtime.h>

// contract(off): numpy-emulating fp32 ops (esq, rescue zsq/dist) must round mul
// and add separately. Explicit fmaf/fma and MFMA are unaffected.
#pragma clang fp contract(off)

#define K_CODES 512
#define D_DIM 256
#define NPIX 65536
#define TAU 3e-4f
#define STRA 264   // A LDS row stride in shorts: 528 B, 16B-aligned
#define CMAX 16    // max stored rescue candidates per pixel (overflow -> full scan)
// z layout [B=64, D=256, H*W=1024]; pixel n = b*1024 + hw.

typedef __attribute__((ext_vector_type(8))) short bf16x8;
typedef __attribute__((ext_vector_type(4))) float f32x4;

// B fragments pre-packed in wave-lane order (validated r8): index
// ((kc*32 + nb)*64 + lane)*8 holds B[n = nb*16 + (lane&15)][k = kc*32 + (lane>>4)*8 + j].
__device__ unsigned short g_bph[8 * 32 * 64 * 8];  // hi
__device__ unsigned short g_bpl[8 * 32 * 64 * 8];  // lo
__device__ float4 g_cbF4[(D_DIM / 4) * K_CODES];   // fp32 cb for rescue (exact)
__device__ float  g_esq[K_CODES];                  // numpy-pairwise fp32 ||e_k||^2
__device__ int    g_list[NPIX];                    // n | (ncand<<16) | overflow<<31
__device__ int    g_cand[NPIX * CMAX];             // candidate code ids per flagged pixel
__device__ int    g_count;

// SESSION LEDGER (geometry space is CLOSED -- do not re-try):
//  r0: acc[4][2] split + launch_bounds(512,4) cap 128 -> spills, 90 MB scratch, 112 us.
//  r1: x2-unroll, 2 named B bufs, setprio -> 140 regs -> 8 waves/CU -> 140 us.
//      Per-occupancy efficiency IDENTICAL (0.65) across all variants: HIP-level
//      scheduling edits do not move per-wave efficiency.
//  r3: candidate-set rescue (scan ~3 codes instead of 512). PASSED 179.0. Validated.
//  r4: rescue fused INTO pass1 -> NONDETERMINISTIC post-timing divergence (absmax 512).
//      Root cause never found. DO NOT re-attempt in-kernel rescue.
//  r5: revert to r3. PASSED 177.0 us = session best. pass1 84.9, VGPR 56+64acc=120,
//      LDS 76.8 KB -> regs AND LDS both bind at exactly 16 waves/CU (balanced point).
//  r6: PPB=32 (acc[2][4], LDS 38 KB) -> compiler rebalanced unified file, VGPR_Count
//      STAYED 120 -> occupancy unmoved; 2x blocks -> 2x B-traffic (1.57 GB L2,
//      per-XCD floor ~46 us) + half work density -> pass1 124 us. REVERTED.
//  Escape routes all blocked: fewer px/block multiplies B traffic (r6); fewer
//  codes/wave needs 16-wave blocks with <=64 total regs (impossible, acc>=32);
//  code-split across blocks needs cross-block merge (r4 race class). Residual
//  ~92 us is harness-fixed (r4: -1 launch = +0; r2: 4x prep parallelism = -2 us).

static __device__ __forceinline__ unsigned short f2bf(float x) {
    unsigned u = __float_as_uint(x);
    return (unsigned short)((u + 0x7FFFu + ((u >> 16) & 1u)) >> 16);   // RNE
}
static __device__ __forceinline__ float bf2f(unsigned short h) {
    return __uint_as_float((unsigned)h << 16);
}

// 64 blocks x 256: thread = (k, kc, quad). Numerics byte-identical to the
// validated 16-block version (same f2bf, same esq pairwise order, same cbF4).
__global__ __launch_bounds__(256) void prep_cb(const float* __restrict__ cb) {
    if (blockIdx.x == 0 && threadIdx.x == 0) g_count = 0;
    const int gt   = blockIdx.x * 256 + threadIdx.x;   // 0..16383
    const int k    = gt >> 5;                          // 0..511
    const int sub  = gt & 31;
    const int kc   = sub >> 2;                         // 0..7
    const int quad = sub & 3;                          // 0..3
    const float* row = cb + k * D_DIM;
    const int nb = k >> 4, nl = k & 15;
    const int lane = quad * 16 + nl;

    unsigned short h8[8], l8[8];
    #pragma unroll
    for (int j = 0; j < 8; ++j) {
        float x = row[kc * 32 + quad * 8 + j];
        h8[j] = f2bf(x);
        l8[j] = f2bf(x - bf2f(h8[j]));   // x-hi exact (Sterbenz)
    }
    const int dst = ((kc * 32 + nb) * 64 + lane) * 8;
    *(uint4*)&g_bph[dst] = *(uint4*)&h8[0];
    *(uint4*)&g_bpl[dst] = *(uint4*)&l8[0];

    // cbF4 scatter distributed: each (k,sub) covers dq = 2*sub, 2*sub+1.
    #pragma unroll
    for (int u = 0; u < 2; ++u) {
        const int dq = sub * 2 + u;
        g_cbF4[dq * K_CODES + k] = make_float4(row[4*dq], row[4*dq+1], row[4*dq+2], row[4*dq+3]);
    }

    if (sub == 0) {
        // e_sq = np.sum(row*row): pairwise n=256 -> p(0:128)+p(128:256); 8 accums each.
        float s[2];
        for (int blk = 0; blk < 2; ++blk) {
            const float* a = row + blk * 128;
            float r[8];
            #pragma unroll
            for (int j = 0; j < 8; ++j) { float x = a[j]; r[j] = x * x; }
            for (int i = 8; i < 128; i += 8)
                #pragma unroll
                for (int j = 0; j < 8; ++j) { float x = a[i + j]; r[j] += x * x; }
            s[blk] = ((r[0] + r[1]) + (r[2] + r[3])) + ((r[4] + r[5]) + (r[6] + r[7]));
        }
        g_esq[k] = s[0] + s[1];
    }
}

// pass1: the GOLDEN structure (85 us, VGPR 56 + 64 acc = 120, 2 blocks/CU;
// regs and LDS both exactly saturated at 16 waves/CU).
__global__ __launch_bounds__(512) void pass1_fused(const float* __restrict__ z,
                                                   int* __restrict__ out) {
    __shared__ unsigned short Az[2][64 * STRA];   // [0]=hi, [1]=lo ; [px][d]
    __shared__ float s_mn[8][64];
    __shared__ int   s_ixl[8][64];
    __shared__ float s_gm[64];
    __shared__ int   s_gi[64];
    __shared__ int   s_ccn[64];
    __shared__ int   s_cand[64][CMAX];

    const int lane = threadIdx.x & 63;
    const int w    = __builtin_amdgcn_readfirstlane((int)(threadIdx.x >> 6));
    const int l16  = lane & 15, quad = lane >> 4;
    const int n0   = (int)blockIdx.x * 64;        // 64 | 1024 -> same b

    // ---- Prologue: stage A (validated r8). wave w: d-chunk [w*32,w*32+32), lane = px.
    {
        const float* zb = z + ((size_t)(n0 >> 10) << 18) + (n0 & 1023);
        const int px = lane, dc = w;
        #pragma unroll
        for (int half = 0; half < 2; ++half) {
            float x[16];
            #pragma unroll
            for (int j = 0; j < 16; ++j)
                x[j] = zb[(size_t)(dc * 32 + half * 16 + j) * 1024 + px]; // coalesced
            unsigned short h[16], l[16];
            #pragma unroll
            for (int j = 0; j < 16; ++j) {
                h[j] = f2bf(x[j]);
                l[j] = f2bf(x[j] - bf2f(h[j]));
            }
            const int o = px * STRA + dc * 32 + half * 16;
            *(uint4*)&Az[0][o]     = *(uint4*)&h[0];
            *(uint4*)&Az[0][o + 8] = *(uint4*)&h[8];
            *(uint4*)&Az[1][o]     = *(uint4*)&l[0];
            *(uint4*)&Az[1][o + 8] = *(uint4*)&l[8];
        }
    }
    __syncthreads();

    f32x4 acc[4][4];
    #pragma unroll
    for (int i = 0; i < 4; ++i)
        #pragma unroll
        for (int j = 0; j < 4; ++j)
            acc[i][j] = (f32x4){0.f, 0.f, 0.f, 0.f};

    // ---- K-loop: 24 steps, no barriers. seg0: zh*ch, seg1: zh*cl, seg2: zl*ch
    // (chain identical to validated r6/r8). B prefetched one step ahead.
    bf16x8 bcur[4];
    #pragma unroll
    for (int tj = 0; tj < 4; ++tj)
        bcur[tj] = *(const bf16x8*)&g_bph[((size_t)(0 * 32 + w * 4 + tj) * 64 + lane) * 8];

    for (int st = 0; st < 24; ++st) {
        const int seg = st >> 3;
        const int kc  = st & 7;
        const unsigned short* As = Az[(seg == 2) ? 1 : 0];

        bf16x8 bnxt[4];
        if (st < 23) {
            const int sp = st + 1;
            const unsigned short* bp = ((sp >> 3) == 1) ? g_bpl : g_bph;
            const int kcn = sp & 7;
            #pragma unroll
            for (int tj = 0; tj < 4; ++tj)   // 1 KB coalesced per wave, L2-hot
                bnxt[tj] = *(const bf16x8*)&bp[((size_t)(kcn * 32 + w * 4 + tj) * 64 + lane) * 8];
        }

        bf16x8 af[4];
        #pragma unroll
        for (int ti = 0; ti < 4; ++ti)
            af[ti] = *(const bf16x8*)&As[(ti * 16 + l16) * STRA + kc * 32 + quad * 8];

        #pragma unroll
        for (int ti = 0; ti < 4; ++ti)
            #pragma unroll
            for (int tj = 0; tj < 4; ++tj)
                acc[ti][tj] = __builtin_amdgcn_mfma_f32_16x16x32_bf16(
                    af[ti], bcur[tj], acc[ti][tj], 0, 0, 0);

        if (st < 23) {
            #pragma unroll
            for (int tj = 0; tj < 4; ++tj) bcur[tj] = bnxt[tj];
        }
    }

    // ---- Epilogue. C/D: col=lane&15 -> n, row=quad*4+r -> m.
    float esqv[4];
    #pragma unroll
    for (int tj = 0; tj < 4; ++tj) esqv[tj] = g_esq[w * 64 + tj * 16 + l16];
    #pragma unroll
    for (int ti = 0; ti < 4; ++ti)
        #pragma unroll
        for (int tj = 0; tj < 4; ++tj)
            #pragma unroll
            for (int r = 0; r < 4; ++r)
                acc[ti][tj][r] = fmaf(-2.0f, acc[ti][tj][r], esqv[tj]);

    #pragma unroll
    for (int ti = 0; ti < 4; ++ti) {
        #pragma unroll
        for (int r = 0; r < 4; ++r) {
            float bv = __builtin_inff(); int bn = 0x7FFFFFFF;
            #pragma unroll
            for (int tj = 0; tj < 4; ++tj) {
                float s = acc[ti][tj][r];
                int nn = w * 64 + tj * 16 + l16;
                if (s < bv || (s == bv && nn < bn)) { bv = s; bn = nn; }
            }
            #pragma unroll
            for (int off = 1; off <= 8; off <<= 1) {
                float ov = __shfl_xor(bv, off); int on = __shfl_xor(bn, off);
                if (ov < bv || (ov == bv && on < bn)) { bv = ov; bn = on; }
            }
            if (l16 == 0) {
                int m = ti * 16 + quad * 4 + r;
                s_mn[w][m] = bv; s_ixl[w][m] = bn;
            }
        }
    }
    __syncthreads();

    if (threadIdx.x < 64) {
        int m = threadIdx.x;
        float gm = s_mn[0][m]; int gi = s_ixl[0][m];
        #pragma unroll
        for (int q = 1; q < 8; ++q) {
            float v = s_mn[q][m]; int ii = s_ixl[q][m];
            if (v < gm || (v == gm && ii < gi)) { gm = v; gi = ii; }
        }
        s_gm[m] = gm; s_gi[m] = gi; s_ccn[m] = 0;
    }
    __syncthreads();

    // Candidate-append pass (validated r3): records {codes with dist < gm+TAU}.
    // List order is atomic-nondeterministic; rescue's lexicographic argmin is
    // order-independent.
    #pragma unroll
    for (int ti = 0; ti < 4; ++ti) {
        #pragma unroll
        for (int r = 0; r < 4; ++r) {
            const int m = ti * 16 + quad * 4 + r;
            const float thr = s_gm[m] + TAU;
            #pragma unroll
            for (int tj = 0; tj < 4; ++tj) {
                if (acc[ti][tj][r] < thr) {
                    int slot = atomicAdd(&s_ccn[m], 1);
                    if (slot < CMAX) s_cand[m][slot] = w * 64 + tj * 16 + l16;
                }
            }
        }
    }
    __syncthreads();

    if (threadIdx.x < 64) {
        int m = threadIdx.x;
        out[n0 + m] = s_gi[m];
        int cnt = s_ccn[m];
        if (cnt >= 2) {
            int pos = atomicAdd(&g_count, 1);
            int ncS = cnt > CMAX ? CMAX : cnt;
            g_list[pos] = (n0 + m) | (ncS << 16) | (cnt > CMAX ? (int)0x80000000 : 0);
            for (int i = 0; i < ncS; ++i) g_cand[pos * CMAX + i] = s_cand[m][i];
        }
    }
}

// Rescue: numpy-bit-exact (validated r3/r5). One wave per flagged pixel.
// Only the recorded candidate codes are recomputed (lane i -> cand[i]);
// per-code math is VERBATIM the validated full-scan body, so each
// candidate's dist is bit-identical to what the full scan would produce.
// The TAU guarantee puts every possible numpy argmin in the candidate set.
// Overflow (>CMAX) pixels take the original full-512 path.
__global__ __launch_bounds__(256) void rescue_kernel(const float* __restrict__ z,
                                                     int* __restrict__ out) {
    const int lane = threadIdx.x & 63;
    const int wg   = (int)blockIdx.x * 4 + (int)(threadIdx.x >> 6);
    const int nw   = (int)gridDim.x * 4;
    const int count = g_count;

    for (int it = wg; it < count; it += nw) {
        const int entry = g_list[it];
        const int n  = entry & 0xFFFF;
        const int nc = (entry >> 16) & 0x1F;
        const bool full = entry < 0;               // overflow -> full scan
        const float* zp = z + ((size_t)(n >> 10) << 18) + (n & 1023);

        float zf[4], xsq[4];
        #pragma unroll
        for (int q = 0; q < 4; ++q) zf[q] = zp[(size_t)((q << 6) + lane) << 10];
        #pragma unroll
        for (int q = 0; q < 4; ++q) xsq[q] = zf[q] * zf[q];

        // numpy pairwise zsq via shuffles (bit-exact, validated r5)
        const int j = lane & 7;
        float r0 = __shfl(xsq[0], j);
        #pragma unroll
        for (int t = 1; t < 8; ++t) r0 += __shfl(xsq[0], 8 * t + j);
        #pragma unroll
        for (int t = 0; t < 8; ++t) r0 += __shfl(xsq[1], 8 * t + j);
        float r1 = __shfl(xsq[2], j);
        #pragma unroll
        for (int t = 1; t < 8; ++t) r1 += __shfl(xsq[2], 8 * t + j);
        #pragma unroll
        for (int t = 0; t < 8; ++t) r1 += __shfl(xsq[3], 8 * t + j);
        r0 = r0 + __shfl_xor(r0, 1); r0 = r0 + __shfl_xor(r0, 2); r0 = r0 + __shfl_xor(r0, 4);
        r1 = r1 + __shfl_xor(r1, 1); r1 = r1 + __shfl_xor(r1, 2); r1 = r1 + __shfl_xor(r1, 4);
        const float zsq = r0 + r1;

        float best = __builtin_inff(); int bi = 0x7FFFFFFF;

        if (!full) {
            // Candidate path: lane i handles candidate i (lanes >= nc duplicate
            // candidate 0 -- idempotent under (dist, idx) min-reduce).
            const int kk = g_cand[it * CMAX + (lane < nc ? lane : 0)];
            double a8a = 0.0, a8b = 0.0;
            for (int dq = 0; dq < D_DIM / 4; ++dq) {
                const int d0 = dq * 4;
                double zd0 = (double)__shfl(zf[(d0    ) >> 6], (d0    ) & 63);
                double zd1 = (double)__shfl(zf[(d0 + 1) >> 6], (d0 + 1) & 63);
                double zd2 = (double)__shfl(zf[(d0 + 2) >> 6], (d0 + 2) & 63);
                double zd3 = (double)__shfl(zf[(d0 + 3) >> 6], (d0 + 3) & 63);
                float4 c4 = g_cbF4[dq * K_CODES + kk];
                a8a = fma((double)c4.x, zd0, a8a);
                a8a = fma((double)c4.y, zd1, a8a);
                a8b = fma((double)c4.z, zd2, a8b);
                a8b = fma((double)c4.w, zd3, a8b);
            }
            float c32 = (float)(a8a + a8b);
            float t = zsq - 2.0f * c32;
            best = t + g_esq[kk];
            bi = kk;
        } else {
            // Original full-512 path, verbatim (overflow fallback).
            double a8a[8], a8b[8];
            #pragma unroll
            for (int jj = 0; jj < 8; ++jj) { a8a[jj] = 0.0; a8b[jj] = 0.0; }
            for (int dq = 0; dq < D_DIM / 4; ++dq) {
                const int d0 = dq * 4;
                double zd0 = (double)__shfl(zf[(d0    ) >> 6], (d0    ) & 63);
                double zd1 = (double)__shfl(zf[(d0 + 1) >> 6], (d0 + 1) & 63);
                double zd2 = (double)__shfl(zf[(d0 + 2) >> 6], (d0 + 2) & 63);
                double zd3 = (double)__shfl(zf[(d0 + 3) >> 6], (d0 + 3) & 63);
                #pragma unroll
                for (int jj = 0; jj < 8; ++jj) {
                    float4 c4 = g_cbF4[dq * K_CODES + lane + (jj << 6)];
                    a8a[jj] = fma((double)c4.x, zd0, a8a[jj]);
                    a8a[jj] = fma((double)c4.y, zd1, a8a[jj]);
                    a8b[jj] = fma((double)c4.z, zd2, a8b[jj]);
                    a8b[jj] = fma((double)c4.w, zd3, a8b[jj]);
                }
            }
            #pragma unroll
            for (int jj = 0; jj < 8; ++jj) {
                int kk = lane + (jj << 6);
                float c32 = (float)(a8a[jj] + a8b[jj]);
                float t = zsq - 2.0f * c32;
                float dist = t + g_esq[kk];
                if (dist < best || (dist == best && kk < bi)) { best = dist; bi = kk; }
            }
        }

        #pragma unroll
        for (int off = 32; off; off >>= 1) {
            float ob = __shfl_xor(best, off);
            int   oi = __shfl_xor(bi, off);
            if (ob < best || (ob == best && oi < bi)) { best = ob; bi = oi; }
        }
        if (lane == 0) out[n] = bi;
    }
}

extern "C" void kernel_launch(void* const* d_in, const int* in_sizes, int n_in,
                              void* d_out, int out_size, void* d_ws, size_t ws_size,
                              hipStream_t stream) {
    const float* z_e_x    = (const float*)d_in[0];   // [64, 256, 32, 32] fp32
    const float* codebook = (const float*)d_in[1];   // [512, 256] fp32
    int* out = (int*)d_out;                          // [65536] int32

    prep_cb<<<dim3(64), dim3(256), 0, stream>>>(codebook);
    pass1_fused<<<dim3(1024), dim3(512), 0, stream>>>(z_e_x, out);
    rescue_kernel<<<dim3(512), dim3(256), 0, stream>>>(z_e_x, out);
}